// Round 1
// baseline (2895.195 us; speedup 1.0000x reference)
//
#include <hip/hip_runtime.h>

// GCN: h = mean-aggregate(feature over incoming edges, fallback feature if deg==0)
//      out = relu(h @ W^T + b)
// N=50000 nodes, E=1600000 edges, D=128.

#define NN 50000
#define EE 1600000
#define DD 128

// ---------------- scatter: summed[dst] += feature[src], deg[dst] += 1 ----------------
// 32 threads per edge, each handles 4 consecutive dims via float4 load + 4 atomicAdds.
__global__ __launch_bounds__(256) void scatter_kernel(
    const float* __restrict__ feature,
    const int* __restrict__ src,
    const int* __restrict__ dst,
    float* __restrict__ summed,
    float* __restrict__ deg) {
  long long t = (long long)blockIdx.x * 256 + threadIdx.x;
  int e = (int)(t >> 5);
  if (e >= EE) return;
  int lane = (int)(t & 31);
  int s = src[e];
  int d = dst[e];
  const float4 v = *((const float4*)(feature + (size_t)s * DD) + lane);
  float* o = summed + (size_t)d * DD + lane * 4;
  atomicAdd(o + 0, v.x);
  atomicAdd(o + 1, v.y);
  atomicAdd(o + 2, v.z);
  atomicAdd(o + 3, v.w);
  if (lane == 0) atomicAdd(deg + d, 1.0f);
}

// ---------------- fused mean + where + GEMM + bias + relu ----------------
// One block = 256 threads, processes 64 nodes. Weight staged transposed in LDS
// (stride 129 pad -> conflict-free writes, 2-way-free reads).
__global__ __launch_bounds__(256) void gemm_kernel(
    const float* __restrict__ summed,
    const float* __restrict__ deg,
    const float* __restrict__ feature,
    const float* __restrict__ weight,   // [128][128] row-major: weight[o][k]
    const float* __restrict__ bias,
    float* __restrict__ out) {
  __shared__ float Wt[DD * 129];   // Wt[k*129 + o] = weight[o][k]  (~66 KB)
  __shared__ float hs[2][DD];

  // stage transposed weight
  for (int i = threadIdx.x; i < DD * DD; i += 256) {
    int o = i >> 7;
    int k = i & 127;
    Wt[k * 129 + o] = weight[i];
  }
  __syncthreads();

  const int base = blockIdx.x * 64;
  const int o    = threadIdx.x & 127;
  const int half = threadIdx.x >> 7;
  const float b  = bias[o];

  for (int it = 0; it < 64; it += 2) {
    // cooperative load of 2 h-rows (mean with zero-deg fallback)
    {
      int nn = base + it + half;
      int k  = threadIdx.x & 127;
      if (nn < NN) {
        float dg = deg[nn];
        float val = (dg > 0.0f) ? summed[(size_t)nn * DD + k] / dg
                                : feature[(size_t)nn * DD + k];
        hs[half][k] = val;
      }
    }
    __syncthreads();

    int n = base + it + half;
    if (n < NN) {
      float acc = b;
#pragma unroll 16
      for (int k = 0; k < DD; ++k) {
        acc = fmaf(hs[half][k], Wt[k * 129 + o], acc);
      }
      out[(size_t)n * DD + o] = acc > 0.0f ? acc : 0.0f;
    }
    __syncthreads();
  }
}

extern "C" void kernel_launch(void* const* d_in, const int* in_sizes, int n_in,
                              void* d_out, int out_size, void* d_ws, size_t ws_size,
                              hipStream_t stream) {
  const float* feature = (const float*)d_in[0];
  const int*   src     = (const int*)d_in[1];
  const int*   dst     = (const int*)d_in[2];
  const float* weight  = (const float*)d_in[3];
  const float* bias    = (const float*)d_in[4];
  float* out = (float*)d_out;

  float* summed = (float*)d_ws;                 // N*128 floats
  float* deg    = summed + (size_t)NN * DD;     // N floats

  size_t zero_bytes = ((size_t)NN * DD + NN) * sizeof(float);
  hipMemsetAsync(d_ws, 0, zero_bytes, stream);

  long long scatter_threads = (long long)EE * 32;
  int scatter_blocks = (int)((scatter_threads + 255) / 256);
  scatter_kernel<<<scatter_blocks, 256, 0, stream>>>(feature, src, dst, summed, deg);

  int gemm_blocks = (NN + 63) / 64;
  gemm_kernel<<<gemm_blocks, 256, 0, stream>>>(summed, deg, feature, weight, bias, out);
}

// Round 2
// 466.708 us; speedup vs baseline: 6.2034x; 6.2034x over previous
//
#include <hip/hip_runtime.h>

// GCN: h = mean-aggregate(feature over incoming edges, fallback feature if deg==0)
//      out = relu(h @ W^T + b)
// N=50000 nodes, E=1600000 edges, D=128.
// R2: scatter->gather via counting-sort CSR (kills 204.8M f32 atomics).

#define NN 50000
#define EE 1600000
#define DD 128

// ---- 1. histogram of in-degrees ----
__global__ __launch_bounds__(256) void hist_kernel(
    const int* __restrict__ dst, int* __restrict__ deg_i) {
  int e = blockIdx.x * 256 + threadIdx.x;
  if (e >= EE) return;
  atomicAdd(&deg_i[dst[e]], 1);
}

// ---- 2. exclusive prefix sum over deg_i -> row_start (single block) ----
__global__ __launch_bounds__(1024) void scan_kernel(
    const int* __restrict__ deg_i, int* __restrict__ row_start) {
  __shared__ int sdata[1024];
  __shared__ int s_off;
  if (threadIdx.x == 0) s_off = 0;
  __syncthreads();
  for (int base = 0; base < NN; base += 1024) {
    int i = base + threadIdx.x;
    int v = (i < NN) ? deg_i[i] : 0;
    sdata[threadIdx.x] = v;
    __syncthreads();
    for (int d = 1; d < 1024; d <<= 1) {
      int t = (threadIdx.x >= d) ? sdata[threadIdx.x - d] : 0;
      __syncthreads();
      sdata[threadIdx.x] += t;
      __syncthreads();
    }
    int off = s_off;
    if (i < NN) row_start[i] = off + sdata[threadIdx.x] - v;
    __syncthreads();
    if (threadIdx.x == 0) s_off = off + sdata[1023];
    __syncthreads();
  }
  if (threadIdx.x == 0) row_start[NN] = s_off;   // == EE
}

// ---- 3. bucket fill: csr_src[row_start[d] + cursor[d]++] = src[e] ----
__global__ __launch_bounds__(256) void fill_kernel(
    const int* __restrict__ src, const int* __restrict__ dst,
    const int* __restrict__ row_start, int* __restrict__ cursor,
    int* __restrict__ csr_src) {
  int e = blockIdx.x * 256 + threadIdx.x;
  if (e >= EE) return;
  int d = dst[e];
  int pos = atomicAdd(&cursor[d], 1);
  csr_src[row_start[d] + pos] = src[e];
}

// ---- 4. gather-aggregate: one wave per node, mean + zero-deg fallback ----
// lane owns float2 at dim lane*2. Writes h to hout (= d_out, overwritten by GEMM).
#define CH 16
__global__ __launch_bounds__(256) void aggregate_kernel(
    const float* __restrict__ feature,
    const int* __restrict__ row_start,
    const int* __restrict__ csr_src,
    float* __restrict__ hout) {
  int wave = threadIdx.x >> 6;
  int lane = threadIdx.x & 63;
  int n = blockIdx.x * 4 + wave;
  if (n >= NN) return;

  int start = row_start[n];
  int end   = row_start[n + 1];
  int deg   = end - start;

  const float2* fp = (const float2*)feature;
  float2 acc = make_float2(0.0f, 0.0f);

  int e = start;
  // full chunks of CH edges, compile-time unrolled for load ILP
  for (; e + CH <= end; e += CH) {
    int idx = csr_src[e + (lane & (CH - 1))];
#pragma unroll
    for (int j = 0; j < CH; ++j) {
      int s = __shfl(idx, j, 64);
      float2 v = fp[(size_t)s * 64 + lane];
      acc.x += v.x; acc.y += v.y;
    }
  }
  // tail
  int rem = end - e;
  if (rem > 0) {
    int idx = (lane < rem) ? csr_src[e + lane] : 0;
    for (int j = 0; j < rem; ++j) {
      int s = __shfl(idx, j, 64);
      float2 v = fp[(size_t)s * 64 + lane];
      acc.x += v.x; acc.y += v.y;
    }
  }

  float2 hv;
  if (deg > 0) {
    float inv = 1.0f / (float)deg;
    hv.x = acc.x * inv; hv.y = acc.y * inv;
  } else {
    hv = fp[(size_t)n * 64 + lane];
  }
  ((float2*)hout)[(size_t)n * 64 + lane] = hv;
}

// ---- 5. fused GEMM + bias + relu, in-place on h (rows staged to LDS first) ----
__global__ __launch_bounds__(256) void gemm_kernel(
    const float* __restrict__ h,        // == out (in-place)
    const float* __restrict__ weight,   // [128][128] row-major: weight[o][k]
    const float* __restrict__ bias,
    float* __restrict__ out) {
  __shared__ float Wt[DD * 129];   // Wt[k*129 + o] = weight[o][k]
  __shared__ float hs[2][DD];

  for (int i = threadIdx.x; i < DD * DD; i += 256) {
    int o = i >> 7;
    int k = i & 127;
    Wt[k * 129 + o] = weight[i];
  }
  __syncthreads();

  const int base = blockIdx.x * 64;
  const int o    = threadIdx.x & 127;
  const int half = threadIdx.x >> 7;
  const float b  = bias[o];

  for (int it = 0; it < 64; it += 2) {
    {
      int nn = base + it + half;
      int k  = threadIdx.x & 127;
      if (nn < NN) hs[half][k] = h[(size_t)nn * DD + k];
    }
    __syncthreads();

    int n = base + it + half;
    if (n < NN) {
      float acc = b;
#pragma unroll 16
      for (int k = 0; k < DD; ++k) {
        acc = fmaf(hs[half][k], Wt[k * 129 + o], acc);
      }
      out[(size_t)n * DD + o] = acc > 0.0f ? acc : 0.0f;
    }
    __syncthreads();
  }
}

extern "C" void kernel_launch(void* const* d_in, const int* in_sizes, int n_in,
                              void* d_out, int out_size, void* d_ws, size_t ws_size,
                              hipStream_t stream) {
  const float* feature = (const float*)d_in[0];
  const int*   src     = (const int*)d_in[1];
  const int*   dst     = (const int*)d_in[2];
  const float* weight  = (const float*)d_in[3];
  const float* bias    = (const float*)d_in[4];
  float* out = (float*)d_out;

  // ws layout (ints): deg_i[N] | cursor[N] | row_start[N+1] | csr_src[E]
  int* deg_i     = (int*)d_ws;
  int* cursor    = deg_i + NN;
  int* row_start = cursor + NN;
  int* csr_src   = row_start + (NN + 1);

  hipMemsetAsync(d_ws, 0, (size_t)2 * NN * sizeof(int), stream);

  hist_kernel<<<(EE + 255) / 256, 256, 0, stream>>>(dst, deg_i);
  scan_kernel<<<1, 1024, 0, stream>>>(deg_i, row_start);
  fill_kernel<<<(EE + 255) / 256, 256, 0, stream>>>(src, dst, row_start, cursor, csr_src);
  aggregate_kernel<<<(NN + 3) / 4, 256, 0, stream>>>(feature, row_start, csr_src, out);
  gemm_kernel<<<(NN + 63) / 64, 256, 0, stream>>>(out, weight, bias, out);
}

// Round 5
// 342.062 us; speedup vs baseline: 8.4639x; 1.3644x over previous
//
#include <hip/hip_runtime.h>

// GCN: h = mean-aggregate(feature over incoming edges, fallback feature if deg==0)
//      out = relu(h @ W^T + b)
// N=50000 nodes, E=1600000 edges, D=128.
// R5 == R3 resubmit (2x infra failure):
// CSR gather (no f32 atomics) + bf16 MFMA GEMM + float4 aggregate + shfl scan.

#define NN 50000
#define EE 1600000
#define DD 128
#define NSTRIP 3125   // 50000 / 16

typedef __attribute__((ext_vector_type(8))) short bf16x8;
typedef __attribute__((ext_vector_type(4))) float f32x4;

static __device__ __forceinline__ short f2bf(float f) {
  union { float f; unsigned u; } x; x.f = f;
  unsigned r = (x.u + 0x7FFF + ((x.u >> 16) & 1)) >> 16;
  return (short)(r & 0xFFFF);
}

// ---- 1. histogram of in-degrees ----
__global__ __launch_bounds__(256) void hist_kernel(
    const int* __restrict__ dst, int* __restrict__ deg_i) {
  int e = blockIdx.x * 256 + threadIdx.x;
  if (e >= EE) return;
  atomicAdd(&deg_i[dst[e]], 1);
}

// ---- 2. exclusive prefix sum (single block, wave-shuffle scan) ----
__global__ __launch_bounds__(1024) void scan_kernel(
    const int* __restrict__ deg_i, int* __restrict__ row_start) {
  __shared__ int wsum[16];
  __shared__ int s_off;
  const int wave = threadIdx.x >> 6;
  const int lane = threadIdx.x & 63;
  if (threadIdx.x == 0) s_off = 0;
  __syncthreads();
  for (int base = 0; base < NN; base += 1024) {
    int i = base + threadIdx.x;
    int v = (i < NN) ? deg_i[i] : 0;
    int x = v;  // wave inclusive scan
#pragma unroll
    for (int d = 1; d < 64; d <<= 1) {
      int t = __shfl_up(x, d, 64);
      if (lane >= d) x += t;
    }
    if (lane == 63) wsum[wave] = x;
    __syncthreads();
    if (threadIdx.x < 16) {
      int w = wsum[threadIdx.x];
#pragma unroll
      for (int d = 1; d < 16; d <<= 1) {
        int t = __shfl_up(w, d, 16);
        if ((threadIdx.x & 15) >= d) w += t;
      }
      wsum[threadIdx.x] = w;  // inclusive
    }
    __syncthreads();
    int off = s_off + ((wave == 0) ? 0 : wsum[wave - 1]);
    if (i < NN) row_start[i] = off + x - v;
    __syncthreads();
    if (threadIdx.x == 0) s_off += wsum[15];
    __syncthreads();
  }
  if (threadIdx.x == 0) row_start[NN] = s_off;  // == EE
}

// ---- 3. bucket fill ----
__global__ __launch_bounds__(256) void fill_kernel(
    const int* __restrict__ src, const int* __restrict__ dst,
    const int* __restrict__ row_start, int* __restrict__ cursor,
    int* __restrict__ csr_src) {
  int e = blockIdx.x * 256 + threadIdx.x;
  if (e >= EE) return;
  int d = dst[e];
  int pos = atomicAdd(&cursor[d], 1);
  csr_src[row_start[d] + pos] = src[e];
}

// ---- 4. gather-aggregate: wave per node, float4/lane, 2 edges in flight ----
// writes h as bf16 [NN][128]
__global__ __launch_bounds__(256) void aggregate_kernel(
    const float* __restrict__ feature,
    const int* __restrict__ row_start,
    const int* __restrict__ csr_src,
    short* __restrict__ hb) {
  const int wave = threadIdx.x >> 6;
  const int lane = threadIdx.x & 63;
  int n = blockIdx.x * 4 + wave;
  if (n >= NN) return;

  const int start = row_start[n];
  const int end   = row_start[n + 1];
  const int deg   = end - start;
  const int half  = lane >> 5;   // which edge of the pair
  const int sl    = lane & 31;   // float4 slot within row

  const float4* fp = (const float4*)feature;  // 32 float4 per row
  float ax = 0.f, ay = 0.f, az = 0.f, aw = 0.f;

#pragma unroll 4
  for (int j = start + half; j < end; j += 2) {
    int s = csr_src[j];
    float4 v = fp[(size_t)s * 32 + sl];
    ax += v.x; ay += v.y; az += v.z; aw += v.w;
  }
  // reduce the two halves
  ax += __shfl_xor(ax, 32, 64);
  ay += __shfl_xor(ay, 32, 64);
  az += __shfl_xor(az, 32, 64);
  aw += __shfl_xor(aw, 32, 64);

  if (half == 0) {
    if (deg > 0) {
      float inv = 1.0f / (float)deg;
      ax *= inv; ay *= inv; az *= inv; aw *= inv;
    } else {
      float4 v = fp[(size_t)n * 32 + sl];
      ax = v.x; ay = v.y; az = v.z; aw = v.w;
    }
    short4 hv;
    hv.x = f2bf(ax); hv.y = f2bf(ay); hv.z = f2bf(az); hv.w = f2bf(aw);
    ((short4*)(hb + (size_t)n * DD))[sl] = hv;
  }
}

// ---- 5. MFMA GEMM: out = relu(h @ W^T + b), h bf16, W cast to bf16 ----
// one wave per 16-row strip; B (whole 128x128 W) in registers.
__global__ __launch_bounds__(256) void mfma_gemm_kernel(
    const short* __restrict__ hb,
    const float* __restrict__ weight,   // [128][128] f32, weight[o][k]
    const float* __restrict__ bias,
    float* __restrict__ out) {
  const int wave = threadIdx.x >> 6;
  const int lane = threadIdx.x & 63;
  const int strip = blockIdx.x * 4 + wave;
  if (strip >= NSTRIP) return;
  const int m0 = strip * 16;
  const int r  = lane & 15;   // row (A) / col (B,D)
  const int g  = lane >> 4;   // k-group, k0 = g*8

  // B fragments: Bf[c][t] holds B[k = t*32+g*8 .. +7][n = c*16+r] = W[n][k...]
  bf16x8 Bf[8][4];
  float bs[8];
#pragma unroll
  for (int c = 0; c < 8; ++c) {
    bs[c] = bias[c * 16 + r];
#pragma unroll
    for (int t = 0; t < 4; ++t) {
      const float* wp = weight + (c * 16 + r) * DD + t * 32 + g * 8;
      float4 w0 = *(const float4*)(wp);
      float4 w1 = *(const float4*)(wp + 4);
      bf16x8 b;
      b[0] = f2bf(w0.x); b[1] = f2bf(w0.y); b[2] = f2bf(w0.z); b[3] = f2bf(w0.w);
      b[4] = f2bf(w1.x); b[5] = f2bf(w1.y); b[6] = f2bf(w1.z); b[7] = f2bf(w1.w);
      Bf[c][t] = b;
    }
  }

  // A fragments: Af[t] holds h[m0 + r][t*32 + g*8 .. +7]
  bf16x8 Af[4];
#pragma unroll
  for (int t = 0; t < 4; ++t) {
    Af[t] = *(const bf16x8*)(hb + (size_t)(m0 + r) * DD + t * 32 + g * 8);
  }

#pragma unroll
  for (int c = 0; c < 8; ++c) {
    f32x4 acc = {0.f, 0.f, 0.f, 0.f};
#pragma unroll
    for (int t = 0; t < 4; ++t) {
      acc = __builtin_amdgcn_mfma_f32_16x16x32_bf16(Af[t], Bf[c][t], acc, 0, 0, 0);
    }
    // D: col = lane&15 (=r), row = g*4 + reg
#pragma unroll
    for (int q = 0; q < 4; ++q) {
      int row = m0 + g * 4 + q;
      float v = acc[q] + bs[c];
      out[(size_t)row * DD + c * 16 + r] = v > 0.f ? v : 0.f;
    }
  }
}

extern "C" void kernel_launch(void* const* d_in, const int* in_sizes, int n_in,
                              void* d_out, int out_size, void* d_ws, size_t ws_size,
                              hipStream_t stream) {
  const float* feature = (const float*)d_in[0];
  const int*   src     = (const int*)d_in[1];
  const int*   dst     = (const int*)d_in[2];
  const float* weight  = (const float*)d_in[3];
  const float* bias    = (const float*)d_in[4];
  float* out = (float*)d_out;

  // ws layout (ints): deg_i[N] | cursor[N] | row_start[N+1] | csr_src[E] | pad | hb (bf16, 16B-aligned)
  int* deg_i     = (int*)d_ws;
  int* cursor    = deg_i + NN;
  int* row_start = cursor + NN;
  int* csr_src   = row_start + (NN + 1);
  short* hb      = (short*)(deg_i + 1750004);  // byte offset 7000016, 16B aligned

  hipMemsetAsync(d_ws, 0, (size_t)2 * NN * sizeof(int), stream);

  hist_kernel<<<(EE + 255) / 256, 256, 0, stream>>>(dst, deg_i);
  scan_kernel<<<1, 1024, 0, stream>>>(deg_i, row_start);
  fill_kernel<<<(EE + 255) / 256, 256, 0, stream>>>(src, dst, row_start, cursor, csr_src);
  aggregate_kernel<<<(NN + 3) / 4, 256, 0, stream>>>(feature, row_start, csr_src, hb);
  mfma_gemm_kernel<<<(NSTRIP + 3) / 4, 256, 0, stream>>>(hb, weight, bias, out);
}

// Round 9
// 313.563 us; speedup vs baseline: 9.2332x; 1.0909x over previous
//
#include <hip/hip_runtime.h>

// GCN: h = mean-aggregate(feature over incoming edges, fallback feature if deg==0)
//      out = relu(h @ W^T + b)
// N=50000 nodes, E=1600000 edges, D=128.
// R9 == R6 resubmit (4x infra failure): bucketed 2-phase CSR build (8 dst-buckets,
// XCD-local fill) to kill the 16x scatter write amplification; parallel scan.

#define NN 50000
#define EE 1600000
#define DD 128
#define NSTRIP 3125    // 50000 / 16
#define NBUCK 8
#define NPBK 6250      // nodes per bucket
#define WCHUNK 1024    // edges per wave-chunk
#define NW 1563        // ceil(EE / WCHUNK)
#define NPB 391        // ceil(NW / 4) blocks for p1/p3
#define NSC 49         // ceil(50001 / 1024) scan blocks
#define FB_PER 32      // fill blocks per bucket

typedef __attribute__((ext_vector_type(8))) short bf16x8;
typedef __attribute__((ext_vector_type(4))) float f32x4;

static __device__ __forceinline__ short f2bf(float f) {
  union { float f; unsigned u; } x; x.f = f;
  unsigned r = (x.u + 0x7FFF + ((x.u >> 16) & 1)) >> 16;
  return (short)(r & 0xFFFF);
}

// ---- P1: per-wave-chunk bucket counts + global deg histogram ----
__global__ __launch_bounds__(256) void p1_count(
    const int* __restrict__ dst, int* __restrict__ deg_i, int* __restrict__ bc) {
  __shared__ int cnt[4][NBUCK];
  const int wv = threadIdx.x >> 6, lane = threadIdx.x & 63;
  const int w = blockIdx.x * 4 + wv;
  if (lane < NBUCK) cnt[wv][lane] = 0;
  __syncthreads();
  if (w < NW) {
    int base = w * WCHUNK;
    for (int i = lane; i < WCHUNK; i += 64) {
      int e = base + i;
      if (e < EE) {
        int d = dst[e];
        atomicAdd(&deg_i[d], 1);
        atomicAdd(&cnt[wv][d / NPBK], 1);
      }
    }
  }
  __syncthreads();
  if (w < NW && lane < NBUCK) bc[lane * NW + w] = cnt[wv][lane];
}

// ---- P2: generic single-block exclusive scan (length n) ----
__global__ __launch_bounds__(1024) void p2_scan(
    const int* __restrict__ in, int* __restrict__ out, int n) {
  __shared__ int ws[16];
  __shared__ int s_off;
  const int wv = threadIdx.x >> 6, lane = threadIdx.x & 63;
  if (threadIdx.x == 0) s_off = 0;
  __syncthreads();
  for (int base = 0; base < n; base += 1024) {
    int i = base + threadIdx.x;
    int v = (i < n) ? in[i] : 0;
    int x = v;
#pragma unroll
    for (int d = 1; d < 64; d <<= 1) { int t = __shfl_up(x, d, 64); if (lane >= d) x += t; }
    if (lane == 63) ws[wv] = x;
    __syncthreads();
    if (threadIdx.x < 16) {
      int w = ws[threadIdx.x];
#pragma unroll
      for (int d = 1; d < 16; d <<= 1) { int t = __shfl_up(w, d, 16); if (threadIdx.x >= d) w += t; }
      ws[threadIdx.x] = w;
    }
    __syncthreads();
    int off = s_off + ((wv == 0) ? 0 : ws[wv - 1]);
    if (i < n) out[i] = off + x - v;
    __syncthreads();
    if (threadIdx.x == 0) s_off += ws[15];
    __syncthreads();
  }
}

// ---- P3: partition edges into 8 dst-buckets (coalesced run writes) ----
__global__ __launch_bounds__(256) void p3_partition(
    const int* __restrict__ src, const int* __restrict__ dst,
    const int* __restrict__ bo, int* __restrict__ psrc, int* __restrict__ pdst) {
  __shared__ int cur[4][NBUCK];
  const int wv = threadIdx.x >> 6, lane = threadIdx.x & 63;
  const int w = blockIdx.x * 4 + wv;
  if (w < NW && lane < NBUCK) cur[wv][lane] = bo[lane * NW + w];
  __syncthreads();
  if (w < NW) {
    int base = w * WCHUNK;
    for (int i = lane; i < WCHUNK; i += 64) {
      int e = base + i;
      if (e < EE) {
        int s = src[e], d = dst[e];
        int pos = atomicAdd(&cur[wv][d / NPBK], 1);
        psrc[pos] = s;
        pdst[pos] = d;
      }
    }
  }
}

// ---- S1/S2/S3: parallel exclusive scan of deg -> row_start ----
__global__ __launch_bounds__(1024) void s1_bsum(
    const int* __restrict__ deg_i, int* __restrict__ bsum) {
  __shared__ int ws[16];
  int i = blockIdx.x * 1024 + threadIdx.x;
  int v = (i < NN) ? deg_i[i] : 0;
#pragma unroll
  for (int d = 1; d < 64; d <<= 1) v += __shfl_xor(v, d, 64);
  int wv = threadIdx.x >> 6, lane = threadIdx.x & 63;
  if (lane == 0) ws[wv] = v;
  __syncthreads();
  if (threadIdx.x == 0) {
    int s = 0;
#pragma unroll
    for (int k = 0; k < 16; ++k) s += ws[k];
    bsum[blockIdx.x] = s;
  }
}

__global__ __launch_bounds__(64) void s2_scan(int* __restrict__ bsum) {
  int t = threadIdx.x;
  int v = (t < NSC) ? bsum[t] : 0;
  int x = v;
#pragma unroll
  for (int d = 1; d < 64; d <<= 1) { int u = __shfl_up(x, d, 64); if (t >= d) x += u; }
  if (t < NSC) bsum[t] = x - v;   // exclusive
}

__global__ __launch_bounds__(1024) void s3_apply(
    const int* __restrict__ deg_i, const int* __restrict__ bsum,
    int* __restrict__ row_start) {
  __shared__ int ws[16];
  int i = blockIdx.x * 1024 + threadIdx.x;
  int wv = threadIdx.x >> 6, lane = threadIdx.x & 63;
  int v = (i < NN) ? deg_i[i] : 0;
  int x = v;
#pragma unroll
  for (int d = 1; d < 64; d <<= 1) { int t = __shfl_up(x, d, 64); if (lane >= d) x += t; }
  if (lane == 63) ws[wv] = x;
  __syncthreads();
  if (threadIdx.x < 16) {
    int w = ws[threadIdx.x];
#pragma unroll
    for (int d = 1; d < 16; d <<= 1) { int t = __shfl_up(w, d, 16); if (threadIdx.x >= d) w += t; }
    ws[threadIdx.x] = w;
  }
  __syncthreads();
  int off = bsum[blockIdx.x] + ((wv == 0) ? 0 : ws[wv - 1]);
  if (i <= NN) row_start[i] = off + x - v;
}

// ---- fillB: per-bucket CSR fill; bucket = blockIdx&7 aligns with XCD round-robin ----
__global__ __launch_bounds__(256) void fillB(
    const int* __restrict__ psrc, const int* __restrict__ pdst,
    const int* __restrict__ bo, const int* __restrict__ row_start,
    int* __restrict__ cursor, int* __restrict__ csr) {
  const int b   = blockIdx.x & 7;
  const int sub = blockIdx.x >> 3;
  const int start = bo[b * NW];
  const int end   = (b == NBUCK - 1) ? EE : bo[(b + 1) * NW];
  for (int e = start + sub * 256 + threadIdx.x; e < end; e += FB_PER * 256) {
    int s = psrc[e], d = pdst[e];
    int pos = atomicAdd(&cursor[d], 1);
    csr[row_start[d] + pos] = s;
  }
}

// ---- aggregate: wave per node, float4/lane, 2 edges in flight; h -> bf16 ----
__global__ __launch_bounds__(256) void aggregate_kernel(
    const float* __restrict__ feature,
    const int* __restrict__ row_start,
    const int* __restrict__ csr_src,
    short* __restrict__ hb) {
  const int wave = threadIdx.x >> 6;
  const int lane = threadIdx.x & 63;
  int n = blockIdx.x * 4 + wave;
  if (n >= NN) return;

  const int start = row_start[n];
  const int end   = row_start[n + 1];
  const int deg   = end - start;
  const int half  = lane >> 5;
  const int sl    = lane & 31;

  const float4* fp = (const float4*)feature;
  float ax = 0.f, ay = 0.f, az = 0.f, aw = 0.f;

#pragma unroll 4
  for (int j = start + half; j < end; j += 2) {
    int s = csr_src[j];
    float4 v = fp[(size_t)s * 32 + sl];
    ax += v.x; ay += v.y; az += v.z; aw += v.w;
  }
  ax += __shfl_xor(ax, 32, 64);
  ay += __shfl_xor(ay, 32, 64);
  az += __shfl_xor(az, 32, 64);
  aw += __shfl_xor(aw, 32, 64);

  if (half == 0) {
    if (deg > 0) {
      float inv = 1.0f / (float)deg;
      ax *= inv; ay *= inv; az *= inv; aw *= inv;
    } else {
      float4 v = fp[(size_t)n * 32 + sl];
      ax = v.x; ay = v.y; az = v.z; aw = v.w;
    }
    short4 hv;
    hv.x = f2bf(ax); hv.y = f2bf(ay); hv.z = f2bf(az); hv.w = f2bf(aw);
    ((short4*)(hb + (size_t)n * DD))[sl] = hv;
  }
}

// ---- MFMA GEMM: out = relu(h @ W^T + b) ----
__global__ __launch_bounds__(256) void mfma_gemm_kernel(
    const short* __restrict__ hb,
    const float* __restrict__ weight,
    const float* __restrict__ bias,
    float* __restrict__ out) {
  const int wave = threadIdx.x >> 6;
  const int lane = threadIdx.x & 63;
  const int strip = blockIdx.x * 4 + wave;
  if (strip >= NSTRIP) return;
  const int m0 = strip * 16;
  const int r  = lane & 15;
  const int g  = lane >> 4;

  bf16x8 Bf[8][4];
  float bs[8];
#pragma unroll
  for (int c = 0; c < 8; ++c) {
    bs[c] = bias[c * 16 + r];
#pragma unroll
    for (int t = 0; t < 4; ++t) {
      const float* wp = weight + (c * 16 + r) * DD + t * 32 + g * 8;
      float4 w0 = *(const float4*)(wp);
      float4 w1 = *(const float4*)(wp + 4);
      bf16x8 b;
      b[0] = f2bf(w0.x); b[1] = f2bf(w0.y); b[2] = f2bf(w0.z); b[3] = f2bf(w0.w);
      b[4] = f2bf(w1.x); b[5] = f2bf(w1.y); b[6] = f2bf(w1.z); b[7] = f2bf(w1.w);
      Bf[c][t] = b;
    }
  }

  bf16x8 Af[4];
#pragma unroll
  for (int t = 0; t < 4; ++t) {
    Af[t] = *(const bf16x8*)(hb + (size_t)(m0 + r) * DD + t * 32 + g * 8);
  }

#pragma unroll
  for (int c = 0; c < 8; ++c) {
    f32x4 acc = {0.f, 0.f, 0.f, 0.f};
#pragma unroll
    for (int t = 0; t < 4; ++t) {
      acc = __builtin_amdgcn_mfma_f32_16x16x32_bf16(Af[t], Bf[c][t], acc, 0, 0, 0);
    }
#pragma unroll
    for (int q = 0; q < 4; ++q) {
      int row = m0 + g * 4 + q;
      float v = acc[q] + bs[c];
      out[(size_t)row * DD + c * 16 + r] = v > 0.f ? v : 0.f;
    }
  }
}

extern "C" void kernel_launch(void* const* d_in, const int* in_sizes, int n_in,
                              void* d_out, int out_size, void* d_ws, size_t ws_size,
                              hipStream_t stream) {
  const float* feature = (const float*)d_in[0];
  const int*   src     = (const int*)d_in[1];
  const int*   dst     = (const int*)d_in[2];
  const float* weight  = (const float*)d_in[3];
  const float* bias    = (const float*)d_in[4];
  float* out = (float*)d_out;

  // ws (ints): deg[50000] cursor[50000] row_start[50001] bc[12504] bo[12504] bsum[64] | hb
  int* deg_i     = (int*)d_ws;
  int* cursor    = deg_i + 50000;
  int* row_start = cursor + 50000;       // 50001
  int* bc        = row_start + 50004;    // at 150004, 12504
  int* bo        = bc + 12508;           // at 162512, 12504
  int* bsum      = bo + 12508;           // at 175020, 64
  short* hb      = (short*)(deg_i + 175104);  // byte 700416, 16B aligned

  // d_out as scratch (ints): psrc[E] pdst[E] csr[E] = 19.2MB <= 25.6MB
  int* psrc = (int*)d_out;
  int* pdst = psrc + EE;
  int* csr  = pdst + EE;

  hipMemsetAsync(d_ws, 0, (size_t)100000 * sizeof(int), stream);  // deg + cursor

  p1_count<<<NPB, 256, 0, stream>>>(dst, deg_i, bc);
  p2_scan<<<1, 1024, 0, stream>>>(bc, bo, NBUCK * NW);
  s1_bsum<<<NSC, 1024, 0, stream>>>(deg_i, bsum);
  s2_scan<<<1, 64, 0, stream>>>(bsum);
  s3_apply<<<NSC, 1024, 0, stream>>>(deg_i, bsum, row_start);
  p3_partition<<<NPB, 256, 0, stream>>>(src, dst, bo, psrc, pdst);
  fillB<<<NBUCK * FB_PER, 256, 0, stream>>>(psrc, pdst, bo, row_start, cursor, csr);
  aggregate_kernel<<<(NN + 3) / 4, 256, 0, stream>>>(feature, row_start, csr, hb);
  mfma_gemm_kernel<<<(NSTRIP + 3) / 4, 256, 0, stream>>>(hb, weight, bias, out);
}

// Round 11
// 271.504 us; speedup vs baseline: 10.6635x; 1.1549x over previous
//
#include <hip/hip_runtime.h>

// GCN: h = mean-aggregate(feature over incoming edges, fallback feature if deg==0)
//      out = relu(h @ W^T + b)
// N=50000 nodes, E=1600000 edges, D=128.
// R11 == R10 + compile fix (hb cast at mfma_gemm call site).
// bf16 feature table for the gather (halves aggregate traffic, 4 edges in
// flight); CSR build unchanged from R9 (bucketed 2-phase, XCD-local fill).

#define NN 50000
#define EE 1600000
#define DD 128
#define NSTRIP 3125    // 50000 / 16
#define NBUCK 8
#define NPBK 6250      // nodes per bucket
#define WCHUNK 1024    // edges per wave-chunk
#define NW 1563        // ceil(EE / WCHUNK)
#define NPB 391        // ceil(NW / 4) blocks for p1/p3
#define NSC 49         // ceil(50001 / 1024) scan blocks
#define FB_PER 32      // fill blocks per bucket

typedef __attribute__((ext_vector_type(8))) short bf16x8;
typedef __attribute__((ext_vector_type(8))) unsigned short u16x8;
typedef __attribute__((ext_vector_type(4))) float f32x4;

static __device__ __forceinline__ short f2bf(float f) {
  union { float f; unsigned u; } x; x.f = f;
  unsigned r = (x.u + 0x7FFF + ((x.u >> 16) & 1)) >> 16;
  return (short)(r & 0xFFFF);
}

// ---- P1: per-wave-chunk bucket counts + global deg histogram ----
__global__ __launch_bounds__(256) void p1_count(
    const int* __restrict__ dst, int* __restrict__ deg_i, int* __restrict__ bc) {
  __shared__ int cnt[4][NBUCK];
  const int wv = threadIdx.x >> 6, lane = threadIdx.x & 63;
  const int w = blockIdx.x * 4 + wv;
  if (lane < NBUCK) cnt[wv][lane] = 0;
  __syncthreads();
  if (w < NW) {
    int base = w * WCHUNK;
    for (int i = lane; i < WCHUNK; i += 64) {
      int e = base + i;
      if (e < EE) {
        int d = dst[e];
        atomicAdd(&deg_i[d], 1);
        atomicAdd(&cnt[wv][d / NPBK], 1);
      }
    }
  }
  __syncthreads();
  if (w < NW && lane < NBUCK) bc[lane * NW + w] = cnt[wv][lane];
}

// ---- P2: generic single-block exclusive scan (length n) ----
__global__ __launch_bounds__(1024) void p2_scan(
    const int* __restrict__ in, int* __restrict__ out, int n) {
  __shared__ int ws[16];
  __shared__ int s_off;
  const int wv = threadIdx.x >> 6, lane = threadIdx.x & 63;
  if (threadIdx.x == 0) s_off = 0;
  __syncthreads();
  for (int base = 0; base < n; base += 1024) {
    int i = base + threadIdx.x;
    int v = (i < n) ? in[i] : 0;
    int x = v;
#pragma unroll
    for (int d = 1; d < 64; d <<= 1) { int t = __shfl_up(x, d, 64); if (lane >= d) x += t; }
    if (lane == 63) ws[wv] = x;
    __syncthreads();
    if (threadIdx.x < 16) {
      int w = ws[threadIdx.x];
#pragma unroll
      for (int d = 1; d < 16; d <<= 1) { int t = __shfl_up(w, d, 16); if (threadIdx.x >= d) w += t; }
      ws[threadIdx.x] = w;
    }
    __syncthreads();
    int off = s_off + ((wv == 0) ? 0 : ws[wv - 1]);
    if (i < n) out[i] = off + x - v;
    __syncthreads();
    if (threadIdx.x == 0) s_off += ws[15];
    __syncthreads();
  }
}

// ---- P3: partition edges into 8 dst-buckets (coalesced run writes) ----
__global__ __launch_bounds__(256) void p3_partition(
    const int* __restrict__ src, const int* __restrict__ dst,
    const int* __restrict__ bo, int* __restrict__ psrc, int* __restrict__ pdst) {
  __shared__ int cur[4][NBUCK];
  const int wv = threadIdx.x >> 6, lane = threadIdx.x & 63;
  const int w = blockIdx.x * 4 + wv;
  if (w < NW && lane < NBUCK) cur[wv][lane] = bo[lane * NW + w];
  __syncthreads();
  if (w < NW) {
    int base = w * WCHUNK;
    for (int i = lane; i < WCHUNK; i += 64) {
      int e = base + i;
      if (e < EE) {
        int s = src[e], d = dst[e];
        int pos = atomicAdd(&cur[wv][d / NPBK], 1);
        psrc[pos] = s;
        pdst[pos] = d;
      }
    }
  }
}

// ---- S1/S2/S3: parallel exclusive scan of deg -> row_start ----
__global__ __launch_bounds__(1024) void s1_bsum(
    const int* __restrict__ deg_i, int* __restrict__ bsum) {
  __shared__ int ws[16];
  int i = blockIdx.x * 1024 + threadIdx.x;
  int v = (i < NN) ? deg_i[i] : 0;
#pragma unroll
  for (int d = 1; d < 64; d <<= 1) v += __shfl_xor(v, d, 64);
  int wv = threadIdx.x >> 6, lane = threadIdx.x & 63;
  if (lane == 0) ws[wv] = v;
  __syncthreads();
  if (threadIdx.x == 0) {
    int s = 0;
#pragma unroll
    for (int k = 0; k < 16; ++k) s += ws[k];
    bsum[blockIdx.x] = s;
  }
}

__global__ __launch_bounds__(64) void s2_scan(int* __restrict__ bsum) {
  int t = threadIdx.x;
  int v = (t < NSC) ? bsum[t] : 0;
  int x = v;
#pragma unroll
  for (int d = 1; d < 64; d <<= 1) { int u = __shfl_up(x, d, 64); if (t >= d) x += u; }
  if (t < NSC) bsum[t] = x - v;   // exclusive
}

__global__ __launch_bounds__(1024) void s3_apply(
    const int* __restrict__ deg_i, const int* __restrict__ bsum,
    int* __restrict__ row_start) {
  __shared__ int ws[16];
  int i = blockIdx.x * 1024 + threadIdx.x;
  int wv = threadIdx.x >> 6, lane = threadIdx.x & 63;
  int v = (i < NN) ? deg_i[i] : 0;
  int x = v;
#pragma unroll
  for (int d = 1; d < 64; d <<= 1) { int t = __shfl_up(x, d, 64); if (lane >= d) x += t; }
  if (lane == 63) ws[wv] = x;
  __syncthreads();
  if (threadIdx.x < 16) {
    int w = ws[threadIdx.x];
#pragma unroll
    for (int d = 1; d < 16; d <<= 1) { int t = __shfl_up(w, d, 16); if (threadIdx.x >= d) w += t; }
    ws[threadIdx.x] = w;
  }
  __syncthreads();
  int off = bsum[blockIdx.x] + ((wv == 0) ? 0 : ws[wv - 1]);
  if (i <= NN) row_start[i] = off + x - v;
}

// ---- fillB: per-bucket CSR fill; bucket = blockIdx&7 aligns with XCD round-robin ----
__global__ __launch_bounds__(256) void fillB(
    const int* __restrict__ psrc, const int* __restrict__ pdst,
    const int* __restrict__ bo, const int* __restrict__ row_start,
    int* __restrict__ cursor, int* __restrict__ csr) {
  const int b   = blockIdx.x & 7;
  const int sub = blockIdx.x >> 3;
  const int start = bo[b * NW];
  const int end   = (b == NBUCK - 1) ? EE : bo[(b + 1) * NW];
  for (int e = start + sub * 256 + threadIdx.x; e < end; e += FB_PER * 256) {
    int s = psrc[e], d = pdst[e];
    int pos = atomicAdd(&cursor[d], 1);
    csr[row_start[d] + pos] = s;
  }
}

// ---- feat2bf: f32 feature -> bf16 table (runs after fillB; fb overlays psrc/pdst) ----
__global__ __launch_bounds__(256) void feat2bf_kernel(
    const float* __restrict__ feature, unsigned short* __restrict__ fb) {
  int i = blockIdx.x * 256 + threadIdx.x;   // one float4 per thread
  if (i < NN * DD / 4) {
    float4 v = ((const float4*)feature)[i];
    short4 o;
    o.x = f2bf(v.x); o.y = f2bf(v.y); o.z = f2bf(v.z); o.w = f2bf(v.w);
    ((short4*)fb)[i] = o;
  }
}

// ---- aggregate: wave per node, u16x8/lane, 16 lanes/row, 4 edges in flight ----
__global__ __launch_bounds__(256) void aggregate_bf16(
    const unsigned short* __restrict__ fb,   // bf16 [NN][128]
    const int* __restrict__ row_start,
    const int* __restrict__ csr_src,
    unsigned short* __restrict__ hb) {
  const int wave = threadIdx.x >> 6;
  const int lane = threadIdx.x & 63;
  int n = blockIdx.x * 4 + wave;
  if (n >= NN) return;

  const int start = row_start[n];
  const int end   = row_start[n + 1];
  const int deg   = end - start;
  const int q  = lane >> 4;   // which of 4 edges in flight
  const int sl = lane & 15;   // 16B slot within 256B row

  const u16x8* fp = (const u16x8*)fb;   // 16 u16x8 per row
  float acc[8];
#pragma unroll
  for (int j = 0; j < 8; ++j) acc[j] = 0.f;

#pragma unroll 4
  for (int e = start + q; e < end; e += 4) {
    int s = csr_src[e];
    u16x8 v = fp[(size_t)s * 16 + sl];
#pragma unroll
    for (int j = 0; j < 8; ++j) {
      union { unsigned u; float f; } c; c.u = ((unsigned)v[j]) << 16;
      acc[j] += c.f;
    }
  }
#pragma unroll
  for (int j = 0; j < 8; ++j) {
    acc[j] += __shfl_xor(acc[j], 16, 64);
    acc[j] += __shfl_xor(acc[j], 32, 64);
  }

  if (q == 0) {
    u16x8 hv;
    if (deg > 0) {
      float inv = 1.0f / (float)deg;
#pragma unroll
      for (int j = 0; j < 8; ++j) hv[j] = (unsigned short)f2bf(acc[j] * inv);
    } else {
      hv = fp[(size_t)n * 16 + sl];   // fallback: bf16(feature) row
    }
    ((u16x8*)hb)[(size_t)n * 16 + sl] = hv;
  }
}

// ---- MFMA GEMM: out = relu(h @ W^T + b) ----
__global__ __launch_bounds__(256) void mfma_gemm_kernel(
    const short* __restrict__ hb,
    const float* __restrict__ weight,
    const float* __restrict__ bias,
    float* __restrict__ out) {
  const int wave = threadIdx.x >> 6;
  const int lane = threadIdx.x & 63;
  const int strip = blockIdx.x * 4 + wave;
  if (strip >= NSTRIP) return;
  const int m0 = strip * 16;
  const int r  = lane & 15;
  const int g  = lane >> 4;

  bf16x8 Bf[8][4];
  float bs[8];
#pragma unroll
  for (int c = 0; c < 8; ++c) {
    bs[c] = bias[c * 16 + r];
#pragma unroll
    for (int t = 0; t < 4; ++t) {
      const float* wp = weight + (c * 16 + r) * DD + t * 32 + g * 8;
      float4 w0 = *(const float4*)(wp);
      float4 w1 = *(const float4*)(wp + 4);
      bf16x8 b;
      b[0] = f2bf(w0.x); b[1] = f2bf(w0.y); b[2] = f2bf(w0.z); b[3] = f2bf(w0.w);
      b[4] = f2bf(w1.x); b[5] = f2bf(w1.y); b[6] = f2bf(w1.z); b[7] = f2bf(w1.w);
      Bf[c][t] = b;
    }
  }

  bf16x8 Af[4];
#pragma unroll
  for (int t = 0; t < 4; ++t) {
    Af[t] = *(const bf16x8*)(hb + (size_t)(m0 + r) * DD + t * 32 + g * 8);
  }

#pragma unroll
  for (int c = 0; c < 8; ++c) {
    f32x4 acc = {0.f, 0.f, 0.f, 0.f};
#pragma unroll
    for (int t = 0; t < 4; ++t) {
      acc = __builtin_amdgcn_mfma_f32_16x16x32_bf16(Af[t], Bf[c][t], acc, 0, 0, 0);
    }
#pragma unroll
    for (int q = 0; q < 4; ++q) {
      int row = m0 + g * 4 + q;
      float v = acc[q] + bs[c];
      out[(size_t)row * DD + c * 16 + r] = v > 0.f ? v : 0.f;
    }
  }
}

extern "C" void kernel_launch(void* const* d_in, const int* in_sizes, int n_in,
                              void* d_out, int out_size, void* d_ws, size_t ws_size,
                              hipStream_t stream) {
  const float* feature = (const float*)d_in[0];
  const int*   src     = (const int*)d_in[1];
  const int*   dst     = (const int*)d_in[2];
  const float* weight  = (const float*)d_in[3];
  const float* bias    = (const float*)d_in[4];
  float* out = (float*)d_out;

  // ws (ints): deg[50000] cursor[50000] row_start[50001] bc[12504] bo[12504] bsum[64] | hb bf16
  int* deg_i     = (int*)d_ws;
  int* cursor    = deg_i + 50000;
  int* row_start = cursor + 50000;       // 50001
  int* bc        = row_start + 50004;    // at 150004, 12504
  int* bo        = bc + 12508;           // at 162512, 12504
  int* bsum      = bo + 12508;           // at 175020, 64
  unsigned short* hb = (unsigned short*)(deg_i + 175104);  // byte 700416, 16B aligned

  // d_out as scratch (ints): psrc[E] pdst[E] csr[E] = 19.2MB <= 25.6MB.
  // After fillB, psrc/pdst are dead -> fb (bf16 feature table, 12.8MB) overlays them.
  int* psrc = (int*)d_out;
  int* pdst = psrc + EE;
  int* csr  = pdst + EE;
  unsigned short* fb = (unsigned short*)d_out;

  (void)hipMemsetAsync(d_ws, 0, (size_t)100000 * sizeof(int), stream);  // deg + cursor

  p1_count<<<NPB, 256, 0, stream>>>(dst, deg_i, bc);
  p2_scan<<<1, 1024, 0, stream>>>(bc, bo, NBUCK * NW);
  s1_bsum<<<NSC, 1024, 0, stream>>>(deg_i, bsum);
  s2_scan<<<1, 64, 0, stream>>>(bsum);
  s3_apply<<<NSC, 1024, 0, stream>>>(deg_i, bsum, row_start);
  p3_partition<<<NPB, 256, 0, stream>>>(src, dst, bo, psrc, pdst);
  fillB<<<NBUCK * FB_PER, 256, 0, stream>>>(psrc, pdst, bo, row_start, cursor, csr);
  feat2bf_kernel<<<(NN * DD / 4 + 255) / 256, 256, 0, stream>>>(feature, fb);
  aggregate_bf16<<<(NN + 3) / 4, 256, 0, stream>>>(fb, row_start, csr, hb);
  mfma_gemm_kernel<<<(NSTRIP + 3) / 4, 256, 0, stream>>>((const short*)hb, weight, bias, out);
}